// Round 4
// baseline (45.575 us; speedup 1.0000x reference)
//
#include <hip/hip_runtime.h>

namespace {

template<int CTRL, int RM>
__device__ __forceinline__ float dpp_mov0(float v) {
  return __int_as_float(__builtin_amdgcn_update_dpp(
      0, __float_as_int(v), CTRL, RM, 0xF, false));
}
template<int CTRL, int RM>
__device__ __forceinline__ float dpp_mov1(float v) {
  return __int_as_float(__builtin_amdgcn_update_dpp(
      0x3f800000, __float_as_int(v), CTRL, RM, 0xF, false));
}

__device__ __forceinline__ float rl(float v, int k) {
  return __int_as_float(__builtin_amdgcn_readlane(__float_as_int(v), k));
}

// lhs = I - h*A = diag(d_n) + h r_i r_k (k<i), h=dt/2, r_n=sqrt(2n+1),
// d_n=1+h(n+1). y = A_bar x via one joint 2-var linear-recurrence scan
// (HW-verified rounds 1-3). Scan matrix entries are data-independent ->
// hoisted per-step snapshots; each apply = 2 DPP + 3 VALU per step.
struct Hoist {
  float cs0, cs1, cs2, cs3, cs4, cs5;
  float gs0, gs1, gs2, gs3, gs4, gs5;
  float r, inv_d, hr, alpha, k2;
};

__device__ __forceinline__ Hoist make_hoist(float dt, int n) {
  float h = 0.5f * dt, fn = (float)n;
  float r = sqrtf(2.f * fn + 1.f);
  float d = 1.f + h * (fn + 1.f);
  float inv_d = 1.f / d;
  float g = (1.f - h * fn) * inv_d;
  float c = g - 1.f;                  // = -h r^2 / d
  Hoist H;
  H.r = r; H.inv_d = inv_d; H.hr = h * r;
  H.alpha = 1.f + h * fn;
  H.k2 = r * (2.f - d) * inv_d;
#define COEF_STEP(IDX, CTRL, RM)                                        \
  H.cs##IDX = c; H.gs##IDX = g;                                         \
  { float cP = dpp_mov0<CTRL, RM>(c);                                   \
    float gP = dpp_mov1<CTRL, RM>(g);                                   \
    c = fmaf(g, cP, c); g = g * gP; }
  COEF_STEP(0, 0x111, 0xF)   // row_shr:1
  COEF_STEP(1, 0x112, 0xF)   // row_shr:2
  COEF_STEP(2, 0x114, 0xF)   // row_shr:4
  COEF_STEP(3, 0x118, 0xF)   // row_shr:8
  COEF_STEP(4, 0x142, 0xA)   // row_bcast15 -> rows 1,3
  COEF_STEP(5, 0x143, 0xC)   // row_bcast31 -> rows 2,3
#undef COEF_STEP
  return H;
}

__device__ __forceinline__ float abar_apply(float x, const Hoist& H) {
  float w1 = H.r * x, w2 = H.k2 * x;
#define APPLY_STEP(IDX, CTRL, RM)                                       \
  { float w1P = dpp_mov0<CTRL, RM>(w1);                                 \
    float w2P = dpp_mov0<CTRL, RM>(w2);                                 \
    w2 = fmaf(H.cs##IDX, w1P, fmaf(H.gs##IDX, w2P, w2));                \
    w1 += w1P; }
  APPLY_STEP(0, 0x111, 0xF)
  APPLY_STEP(1, 0x112, 0xF)
  APPLY_STEP(2, 0x114, 0xF)
  APPLY_STEP(3, 0x118, 0xF)
  APPLY_STEP(4, 0x142, 0xA)
  APPLY_STEP(5, 0x143, 0xC)
#undef APPLY_STEP
  float tp = dpp_mov0<0x138, 0xF>(w2);           // wave_shr:1 -> T_{i-1}
  return H.inv_d * fmaf(-H.hr, w1 + tp, H.alpha * x);
}

template<int CTRL, int RM>
__device__ __forceinline__ void linrec_step(float& G, float& W) {
  float Wo = dpp_mov0<CTRL, RM>(W);
  float Go = dpp_mov1<CTRL, RM>(G);
  W = fmaf(G, Wo, W);
  G *= Go;
}
__device__ __forceinline__ float lhs_solve(float z, const Hoist& H) {
  float G = H.gs0, W = H.r * z * H.inv_d;
  linrec_step<0x111, 0xF>(G, W);
  linrec_step<0x112, 0xF>(G, W);
  linrec_step<0x114, 0xF>(G, W);
  linrec_step<0x118, 0xF>(G, W);
  linrec_step<0x142, 0xA>(G, W);
  linrec_step<0x143, 0xC>(G, W);
  float sp = dpp_mov0<0x138, 0xF>(W);
  return (z - H.hr * sp) * H.inv_d;
}

__device__ __forceinline__ float softplus_dt(float ldt) {
  return log1pf(expf(ldt)) + 1e-6f;
}

// result[lane] = sum_k M[lane][k] * u[k], M row-major in GLOBAL (L2-hot),
// one float4 live at a time (no big register array).
__device__ __forceinline__ float grow_matvec(const float* __restrict__ M,
                                             float u, int lane) {
  float a0 = 0.f, a1 = 0.f, a2 = 0.f, a3 = 0.f;
  const float4* m4 = (const float4*)(M + lane * 64);
  #pragma unroll
  for (int q = 0; q < 16; ++q) {
    float4 f = m4[q];
    a0 = fmaf(f.x, rl(u, 4 * q + 0), a0);
    a1 = fmaf(f.y, rl(u, 4 * q + 1), a1);
    a2 = fmaf(f.z, rl(u, 4 * q + 2), a2);
    a3 = fmaf(f.w, rl(u, 4 * q + 3), a3);
  }
  return (a0 + a1) + (a2 + a3);
}

// result[lane] = sum_k Q2T[k][lane] * u[k]; Q2T row reads are bank-free
// (row-uniform k, lanes contiguous), u broadcast via readlane.
__device__ __forceinline__ float q2t_matvec(const float* Q2T, float u, int lane) {
  float a0 = 0.f, a1 = 0.f, a2 = 0.f, a3 = 0.f;
  #pragma unroll
  for (int k = 0; k < 64; k += 4) {
    float q0 = Q2T[(k + 0) * 64 + lane];
    float q1 = Q2T[(k + 1) * 64 + lane];
    float q2 = Q2T[(k + 2) * 64 + lane];
    float q3 = Q2T[(k + 3) * 64 + lane];
    a0 = fmaf(q0, rl(u, k + 0), a0);
    a1 = fmaf(q1, rl(u, k + 1), a1);
    a2 = fmaf(q2, rl(u, k + 2), a2);
    a3 = fmaf(q3, rl(u, k + 3), a3);
  }
  return (a0 + a1) + (a2 + a3);
}

} // namespace

// Prep: block m chains e_m through 128 applies.
//   s=32 : col m of A32  -> row-major A32c (A32c[n][k]=A32[n][k], scattered)
//   s=64 : col m of A64  = row m of Q=A64^T  -> QROW  (coalesced)
//   s=128: col m of A128 = row m of Q^2      -> Q2ROW (coalesced)
__global__ __launch_bounds__(64) void hippo_pow(const float* __restrict__ ldt_p,
                                                float* __restrict__ A32c,
                                                float* __restrict__ QROW,
                                                float* __restrict__ Q2ROW) {
  const int lane = threadIdx.x;
  const int m = blockIdx.x;
  const float dt = softplus_dt(ldt_p[0]);
  const Hoist H = make_hoist(dt, lane);
  float x = (lane == m) ? 1.f : 0.f;
  #pragma unroll 1
  for (int s = 0; s < 32; ++s) x = abar_apply(x, H);
  A32c[lane * 64 + m] = x;
  #pragma unroll 1
  for (int s = 0; s < 32; ++s) x = abar_apply(x, H);
  QROW[m * 64 + lane] = x;
  #pragma unroll 1
  for (int s = 0; s < 64; ++s) x = abar_apply(x, H);
  Q2ROW[m * 64 + lane] = x;
}

// Main: per d. wave0: V[0..31]; wave3: V[32..63]; wave1: U even; wave2: U odd;
// all: 32x64 dot epilogue. No thread-private array exceeds 16 elements.
__global__ __launch_bounds__(256, 4) void hippo_main(
    const float* __restrict__ B, const float* __restrict__ C,
    const float* __restrict__ Dv, const float* __restrict__ ldt_p,
    const float* __restrict__ A32c, const float* __restrict__ QROW,
    const float* __restrict__ Q2ROW, float* __restrict__ out, int NI, int L) {
  __shared__ __align__(16) float Vl[64 * 64];   // word = j*64 + (n ^ (j&31))
  __shared__ __align__(16) float Ul[32 * 64];   // row-major
  __shared__ __align__(16) float Q2T[64 * 64];  // Q2T[k][n] = Q2[n][k]
  const int d = blockIdx.x;
  const int tau = threadIdx.x;
  const int lane = tau & 63;
  const int w = tau >> 6;

  if (w == 0) {
    const Hoist H = make_hoist(softplus_dt(ldt_p[0]), lane);
    float v = lhs_solve(softplus_dt(ldt_p[0]) * B[d * 64 + lane], H);
    #pragma unroll 1
    for (int j = 0; j < 32; ++j) {
      Vl[j * 64 + (lane ^ (j & 31))] = v;       // row-uniform write: bank-free
      if (j < 31) v = abar_apply(v, H);
    }
  } else if (w == 3) {
    const Hoist H = make_hoist(softplus_dt(ldt_p[0]), lane);
    float bb = lhs_solve(softplus_dt(ldt_p[0]) * B[d * 64 + lane], H);
    float v = grow_matvec(A32c, bb, lane);      // V32 = A32 * B_bar
    #pragma unroll 1
    for (int j = 32; j < 64; ++j) {
      Vl[j * 64 + (lane ^ (j & 31))] = v;
      if (j < 63) v = abar_apply(v, H);
    }
  } else {
    // Each U-wave stages the FULL Q2T itself (identical duplicate writes are
    // benign; no cross-wave dependency, so no extra barrier). Lane l copies
    // row l of Q2 into column l of Q2T: writes word k*64+l -> bank-free.
    #pragma unroll
    for (int q = 0; q < 16; ++q) {
      float4 f = *(const float4*)(Q2ROW + lane * 64 + 4 * q);
      Q2T[(4 * q + 0) * 64 + lane] = f.x;
      Q2T[(4 * q + 1) * 64 + lane] = f.y;
      Q2T[(4 * q + 2) * 64 + lane] = f.z;
      Q2T[(4 * q + 3) * 64 + lane] = f.w;
    }
    if (w == 1) {
      float u = C[d * 64 + lane];
      const int nE = (NI + 1) >> 1;
      #pragma unroll 1
      for (int a = 0; a < nE; ++a) {
        Ul[(2 * a) * 64 + lane] = u;
        if (a < nE - 1) u = q2t_matvec(Q2T, u, lane);
      }
    } else {  // w == 2
      float u = grow_matvec(QROW, C[d * 64 + lane], lane);   // u1 = Q u0
      const int nO = NI >> 1;
      #pragma unroll 1
      for (int a = 0; a < nO; ++a) {
        Ul[(2 * a + 1) * 64 + lane] = u;
        if (a < nO - 1) u = q2t_matvec(Q2T, u, lane);
      }
    }
  }
  __syncthreads();

  // Epilogue: K[d, i*64+j] = dot(U[i], V[j]); j = lane, i = w + 4k.
  // n-tiled in 4 passes of 16 -> vr[16] + acc[8] stay register-resident.
  const int j = lane;
  float acc[8];
  #pragma unroll
  for (int k = 0; k < 8; ++k) acc[k] = 0.f;
  #pragma unroll
  for (int h = 0; h < 4; ++h) {
    float vr[16];
    #pragma unroll
    for (int e = 0; e < 16; ++e)
      vr[e] = Vl[j * 64 + ((16 * h + e) ^ (j & 31))];  // bank-free (XOR swz)
    #pragma unroll
    for (int k = 0; k < 8; ++k) {
      const int i = w + 4 * k;
      if (i < NI) {
        const float4* u4 = (const float4*)(Ul + i * 64 + 16 * h);  // uniform
        float4 f0 = u4[0], f1 = u4[1], f2 = u4[2], f3 = u4[3];
        acc[k] = fmaf(vr[0],  f0.x, acc[k]);
        acc[k] = fmaf(vr[1],  f0.y, acc[k]);
        acc[k] = fmaf(vr[2],  f0.z, acc[k]);
        acc[k] = fmaf(vr[3],  f0.w, acc[k]);
        acc[k] = fmaf(vr[4],  f1.x, acc[k]);
        acc[k] = fmaf(vr[5],  f1.y, acc[k]);
        acc[k] = fmaf(vr[6],  f1.z, acc[k]);
        acc[k] = fmaf(vr[7],  f1.w, acc[k]);
        acc[k] = fmaf(vr[8],  f2.x, acc[k]);
        acc[k] = fmaf(vr[9],  f2.y, acc[k]);
        acc[k] = fmaf(vr[10], f2.z, acc[k]);
        acc[k] = fmaf(vr[11], f2.w, acc[k]);
        acc[k] = fmaf(vr[12], f3.x, acc[k]);
        acc[k] = fmaf(vr[13], f3.y, acc[k]);
        acc[k] = fmaf(vr[14], f3.z, acc[k]);
        acc[k] = fmaf(vr[15], f3.w, acc[k]);
      }
    }
  }
  #pragma unroll
  for (int k = 0; k < 8; ++k) {
    const int i = w + 4 * k;
    if (i < NI) {
      float y = acc[k];
      if ((i | j) == 0) y += Dv[d];
      out[(size_t)d * L + i * 64 + j] = y;   // coalesced
    }
  }
}

extern "C" void kernel_launch(void* const* d_in, const int* in_sizes, int n_in,
                              void* d_out, int out_size, void* d_ws, size_t ws_size,
                              hipStream_t stream) {
  const float* B   = (const float*)d_in[0];
  const float* C   = (const float*)d_in[1];
  const float* Dv  = (const float*)d_in[2];
  const float* ldt = (const float*)d_in[3];
  const int d_model = in_sizes[2];        // 1024
  const int L = out_size / d_model;       // 2048
  const int NI = L / 64;                  // 32
  float* A32c  = (float*)d_ws;            // 16 KiB
  float* QROW  = (float*)d_ws + 4096;     // 16 KiB
  float* Q2ROW = (float*)d_ws + 8192;     // 16 KiB
  hippo_pow<<<64, 64, 0, stream>>>(ldt, A32c, QROW, Q2ROW);
  hippo_main<<<d_model, 256, 0, stream>>>(B, C, Dv, ldt, A32c, QROW, Q2ROW,
                                          (float*)d_out, NI, L);
}

// Round 5
// 43.681 us; speedup vs baseline: 1.0434x; 1.0434x over previous
//
#include <hip/hip_runtime.h>

namespace {

template<int CTRL, int RM>
__device__ __forceinline__ float dpp_mov0(float v) {
  return __int_as_float(__builtin_amdgcn_update_dpp(
      0, __float_as_int(v), CTRL, RM, 0xF, false));
}
template<int CTRL, int RM>
__device__ __forceinline__ float dpp_mov1(float v) {
  return __int_as_float(__builtin_amdgcn_update_dpp(
      0x3f800000, __float_as_int(v), CTRL, RM, 0xF, false));
}

__device__ __forceinline__ float rl(float v, int k) {
  return __int_as_float(__builtin_amdgcn_readlane(__float_as_int(v), k));
}

// lhs = I - h*A = diag(d_n) + h r_i r_k (k<i), h=dt/2, r_n=sqrt(2n+1),
// d_n=1+h(n+1). y = A_bar x via one joint 2-var linear-recurrence DPP scan
// (HW-verified rounds 1-4, absmax 2.4e-4). Coefs hoisted (data-independent).
struct Hoist {
  float cs0, cs1, cs2, cs3, cs4, cs5;
  float gs0, gs1, gs2, gs3, gs4, gs5;
  float r, inv_d, hr, alpha, k2;
};

__device__ __forceinline__ Hoist make_hoist(float dt, int n) {
  float h = 0.5f * dt, fn = (float)n;
  float r = sqrtf(2.f * fn + 1.f);
  float d = 1.f + h * (fn + 1.f);
  float inv_d = 1.f / d;
  float g = (1.f - h * fn) * inv_d;
  float c = g - 1.f;                  // = -h r^2 / d
  Hoist H;
  H.r = r; H.inv_d = inv_d; H.hr = h * r;
  H.alpha = 1.f + h * fn;
  H.k2 = r * (2.f - d) * inv_d;
#define COEF_STEP(IDX, CTRL, RM)                                        \
  H.cs##IDX = c; H.gs##IDX = g;                                         \
  { float cP = dpp_mov0<CTRL, RM>(c);                                   \
    float gP = dpp_mov1<CTRL, RM>(g);                                   \
    c = fmaf(g, cP, c); g = g * gP; }
  COEF_STEP(0, 0x111, 0xF)   // row_shr:1
  COEF_STEP(1, 0x112, 0xF)   // row_shr:2
  COEF_STEP(2, 0x114, 0xF)   // row_shr:4
  COEF_STEP(3, 0x118, 0xF)   // row_shr:8
  COEF_STEP(4, 0x142, 0xA)   // row_bcast15 -> rows 1,3
  COEF_STEP(5, 0x143, 0xC)   // row_bcast31 -> rows 2,3
#undef COEF_STEP
  return H;
}

__device__ __forceinline__ float abar_apply(float x, const Hoist& H) {
  float w1 = H.r * x, w2 = H.k2 * x;
#define APPLY_STEP(IDX, CTRL, RM)                                       \
  { float w1P = dpp_mov0<CTRL, RM>(w1);                                 \
    float w2P = dpp_mov0<CTRL, RM>(w2);                                 \
    w2 = fmaf(H.cs##IDX, w1P, fmaf(H.gs##IDX, w2P, w2));                \
    w1 += w1P; }
  APPLY_STEP(0, 0x111, 0xF)
  APPLY_STEP(1, 0x112, 0xF)
  APPLY_STEP(2, 0x114, 0xF)
  APPLY_STEP(3, 0x118, 0xF)
  APPLY_STEP(4, 0x142, 0xA)
  APPLY_STEP(5, 0x143, 0xC)
#undef APPLY_STEP
  float tp = dpp_mov0<0x138, 0xF>(w2);           // wave_shr:1 -> T_{i-1}
  return H.inv_d * fmaf(-H.hr, w1 + tp, H.alpha * x);
}

template<int CTRL, int RM>
__device__ __forceinline__ void linrec_step(float& G, float& W) {
  float Wo = dpp_mov0<CTRL, RM>(W);
  float Go = dpp_mov1<CTRL, RM>(G);
  W = fmaf(G, Wo, W);
  G *= Go;
}
__device__ __forceinline__ float lhs_solve(float z, const Hoist& H) {
  float G = H.gs0, W = H.r * z * H.inv_d;
  linrec_step<0x111, 0xF>(G, W);
  linrec_step<0x112, 0xF>(G, W);
  linrec_step<0x114, 0xF>(G, W);
  linrec_step<0x118, 0xF>(G, W);
  linrec_step<0x142, 0xA>(G, W);
  linrec_step<0x143, 0xC>(G, W);
  float sp = dpp_mov0<0x138, 0xF>(W);
  return (z - H.hr * sp) * H.inv_d;
}

__device__ __forceinline__ float softplus_dt(float ldt) {
  return log1pf(expf(ldt)) + 1e-6f;
}

// pc[k] = M[lane][k] from global (L2-hot), into registers. VMEM pipe only.
__device__ __forceinline__ void load_row_g(const float* __restrict__ base,
                                           float (&pc)[64]) {
  const float4* p4 = (const float4*)base;
  #pragma unroll
  for (int q = 0; q < 16; ++q) {
    float4 f = p4[q];
    pc[4*q+0] = f.x; pc[4*q+1] = f.y; pc[4*q+2] = f.z; pc[4*q+3] = f.w;
  }
}

// res[lane] = sum_k pc[k] * u[k]; u distributed (lane k holds u[k]),
// broadcast via readlane. Pure VALU, zero DS.
__device__ __forceinline__ float qapply(const float (&pc)[64], float u) {
  float a0 = 0.f, a1 = 0.f, a2 = 0.f, a3 = 0.f;
  #pragma unroll
  for (int k = 0; k < 64; k += 4) {
    a0 = fmaf(pc[k + 0], rl(u, k + 0), a0);
    a1 = fmaf(pc[k + 1], rl(u, k + 1), a1);
    a2 = fmaf(pc[k + 2], rl(u, k + 2), a2);
    a3 = fmaf(pc[k + 3], rl(u, k + 3), a3);
  }
  return (a0 + a1) + (a2 + a3);
}

// streaming matvec from global row (one float4 live at a time)
__device__ __forceinline__ float grow_matvec(const float* __restrict__ M,
                                             float u, int lane) {
  float a0 = 0.f, a1 = 0.f, a2 = 0.f, a3 = 0.f;
  const float4* m4 = (const float4*)(M + lane * 64);
  #pragma unroll
  for (int q = 0; q < 16; ++q) {
    float4 f = m4[q];
    a0 = fmaf(f.x, rl(u, 4 * q + 0), a0);
    a1 = fmaf(f.y, rl(u, 4 * q + 1), a1);
    a2 = fmaf(f.z, rl(u, 4 * q + 2), a2);
    a3 = fmaf(f.w, rl(u, 4 * q + 3), a3);
  }
  return (a0 + a1) + (a2 + a3);
}

// V storage swizzle: 16B-granular XOR within each 64-word row ->
// b128 row reads and b32 row-uniform writes both bank-spread.
__device__ __forceinline__ int vidx(int j, int n) {
  return j * 64 + ((((n >> 2) ^ (j & 15)) << 2) | (n & 3));
}

} // namespace

// Prep: block m chains e_m through 64 applies.
//   s=32: col m of A32 -> row-major A32c[n][k]
//   s=64: col m of A64 -> QROW[m][k] = A64[k][m] = Q-row m  (coalesced)
__global__ __launch_bounds__(64) void hippo_pow(const float* __restrict__ ldt_p,
                                                float* __restrict__ A32c,
                                                float* __restrict__ QROW) {
  const int lane = threadIdx.x;
  const int m = blockIdx.x;
  const float dt = softplus_dt(ldt_p[0]);
  const Hoist H = make_hoist(dt, lane);
  float x = (lane == m) ? 1.f : 0.f;
  #pragma unroll 1
  for (int s = 0; s < 32; ++s) x = abar_apply(x, H);
  A32c[lane * 64 + m] = x;
  #pragma unroll 1
  for (int s = 0; s < 32; ++s) x = abar_apply(x, H);
  QROW[m * 64 + lane] = x;
}

// Main: roles rotated per block so same-role waves spread across SIMDs.
//  role0: V[0..31] chain; role3: V[32..63] (A32 seed); role1: full U chain
//  (31 register matvecs); role2: idle until epilogue. Epilogue: all waves,
//  U broadcast via readlane from 8 per-lane regs, V via swizzled b128.
__global__ __launch_bounds__(256, 2) void hippo_main(
    const float* __restrict__ B, const float* __restrict__ C,
    const float* __restrict__ Dv, const float* __restrict__ ldt_p,
    const float* __restrict__ A32c, const float* __restrict__ QROW,
    float* __restrict__ out, int NI, int L) {
  __shared__ __align__(16) float Vl[64 * 64];   // swizzled via vidx()
  __shared__ __align__(16) float Ul[32 * 64];   // row-major
  const int d = blockIdx.x;
  const int tau = threadIdx.x;
  const int lane = tau & 63;
  const int w = tau >> 6;
  const int role = (w + d) & 3;
  const float dt = softplus_dt(ldt_p[0]);

  if (role == 0) {
    const Hoist H = make_hoist(dt, lane);
    float v = lhs_solve(dt * B[d * 64 + lane], H);
    #pragma unroll 1
    for (int j = 0; j < 32; ++j) {
      Vl[vidx(j, lane)] = v;                    // bank-spread write
      if (j < 31) v = abar_apply(v, H);
    }
  } else if (role == 3) {
    const Hoist H = make_hoist(dt, lane);
    float bb = lhs_solve(dt * B[d * 64 + lane], H);
    float v = grow_matvec(A32c, bb, lane);      // V32 = A32 * B_bar
    #pragma unroll 1
    for (int j = 32; j < 64; ++j) {
      Vl[vidx(j, lane)] = v;
      if (j < 63) v = abar_apply(v, H);
    }
  } else if (role == 1) {
    float pc[64];
    load_row_g(QROW + lane * 64, pc);           // pc[k] = Q[lane][k]
    float u = C[d * 64 + lane];
    #pragma unroll 1
    for (int i = 0; i < NI; ++i) {
      Ul[i * 64 + lane] = u;                    // 1 ds_write_b32 per i
      if (i < NI - 1) u = qapply(pc, u);        // pure VALU
    }
  }
  // role 2: no chain work
  __syncthreads();

  // Epilogue: K[d, i*64+j] = dot(U[i], V[j]); j = lane, i = w + 4k.
  const int j = lane;
  float ureg[8];
  #pragma unroll
  for (int k = 0; k < 8; ++k) {
    const int i = w + 4 * k;
    ureg[k] = (i < NI) ? Ul[i * 64 + lane] : 0.f;   // 8 b32, bank-free
  }
  float acc[8];
  #pragma unroll
  for (int k = 0; k < 8; ++k) acc[k] = 0.f;
  #pragma unroll
  for (int h = 0; h < 4; ++h) {
    float vr[16];
    #pragma unroll
    for (int q4 = 0; q4 < 4; ++q4) {
      const int q = h * 4 + q4;
      float4 f = *(const float4*)&Vl[j * 64 + ((q ^ (j & 15)) << 2)];
      vr[4*q4+0] = f.x; vr[4*q4+1] = f.y; vr[4*q4+2] = f.z; vr[4*q4+3] = f.w;
    }
    #pragma unroll
    for (int k = 0; k < 8; ++k) {
      #pragma unroll
      for (int e = 0; e < 16; ++e) {
        acc[k] = fmaf(vr[e], rl(ureg[k], 16 * h + e), acc[k]);
      }
    }
  }
  #pragma unroll
  for (int k = 0; k < 8; ++k) {
    const int i = w + 4 * k;
    if (i < NI) {
      float y = acc[k];
      if ((i | j) == 0) y += Dv[d];
      out[(size_t)d * L + i * 64 + j] = y;   // coalesced
    }
  }
}

extern "C" void kernel_launch(void* const* d_in, const int* in_sizes, int n_in,
                              void* d_out, int out_size, void* d_ws, size_t ws_size,
                              hipStream_t stream) {
  const float* B   = (const float*)d_in[0];
  const float* C   = (const float*)d_in[1];
  const float* Dv  = (const float*)d_in[2];
  const float* ldt = (const float*)d_in[3];
  const int d_model = in_sizes[2];        // 1024
  const int L = out_size / d_model;       // 2048
  const int NI = L / 64;                  // 32
  float* A32c = (float*)d_ws;             // 16 KiB
  float* QROW = (float*)d_ws + 4096;      // 16 KiB
  hippo_pow<<<64, 64, 0, stream>>>(ldt, A32c, QROW);
  hippo_main<<<1024, 256, 0, stream>>>(B, C, Dv, ldt, A32c, QROW,
                                       (float*)d_out, NI, L);
}